// Round 6
// baseline (152.255 us; speedup 1.0000x reference)
//
#include <hip/hip_runtime.h>

// x: (2,8,256,256) fp32, F: 3x3 fp32.
#define HS 256
#define WSZ 256
#define NPIX (HS * WSZ)        // 65536 pixels
#define NCH 16                 // B*C
#define NELEM (NPIX * NCH)

// ---------------------------------------------------------------------------
// Transpose (bc, h, w) -> (h, w, bc): one pixel's 16 channels = one 64B line.
// ---------------------------------------------------------------------------
__global__ __launch_bounds__(256) void transpose_kernel(const float* __restrict__ x,
                                                        float* __restrict__ T) {
    int tid = blockIdx.x * 256 + threadIdx.x;
    int bc  = tid >> 16;
    int pix = tid & 65535;
    T[pix * NCH + bc] = x[tid];
}

// ---------------------------------------------------------------------------
// Geometry: FMA-contracted einsum, j ascending (verified direction R4):
//   l_i = fma(F[2,i], 1, fma(F[1,i], v, F[0,i]*u))
// eps-replace / mode-select in f32.
// ---------------------------------------------------------------------------
struct LineGeom {
    float p, q, c;   // slope coef, safe denominator, constant (all f32)
    bool  col;
};

__device__ __forceinline__ LineGeom make_geom(const float* __restrict__ F, int pix) {
#pragma clang fp contract(off)
    int w = pix & (WSZ - 1);
    int h = pix >> 8;
    float u = (float)w, v = (float)h;
    float a = __builtin_fmaf(F[3], v, F[0] * u) + F[6];
    float b = __builtin_fmaf(F[4], v, F[1] * u) + F[7];
    float c = __builtin_fmaf(F[5], v, F[2] * u) + F[8];
    const float eps = 1e-8f;
    float bs = (fabsf(b) < eps) ? eps : b;
    float as = (fabsf(a) < eps) ? eps : a;
    LineGeom g;
    g.col = (fabsf(b) >= fabsf(a));
    g.p   = g.col ? a : b;
    g.q   = g.col ? bs : as;
    g.c   = c;
    return g;
}

// Per-sample chain: f32 with CONTRACTED mul+add (XLA-CPU-style fp contraction):
//   t = fma(a, xf, c); y = (-t)/b_safe  (IEEE f32 div); rint half-even; int32.
__device__ __forceinline__ int sample_row(const LineGeom& g, int s) {
#pragma clang fp contract(off)
    float sf = (float)s;
    float t  = __builtin_fmaf(g.p, sf, g.c);   // single rounding: fl32(a*x + c)
    float y  = (-t) / g.q;                     // IEEE f32 divide
    float yr = __builtin_rintf(y);             // round half to even
    int   yi = (int)yr;
    bool valid = (yi >= 0) && (yi < HS);
    int  tcl   = min(max(yi, 0), HS - 1);
    return valid ? tcl : -1;
}

// ---------------------------------------------------------------------------
// Gather: thread = (pixel, channel-quad); 4 lanes of one pixel cover the full
// 64B line of the transposed image per sample.
// ---------------------------------------------------------------------------
__global__ __launch_bounds__(256) void epi_gather(const float4* __restrict__ T4,
                                                  const float* __restrict__ F,
                                                  float* __restrict__ out) {
    int tid  = blockIdx.x * 256 + threadIdx.x;
    int quad = tid & 3;
    int pix  = tid >> 2;

    LineGeom g = make_geom(F, pix);

    float4 acc = make_float4(0.f, 0.f, 0.f, 0.f);

#pragma unroll 4
    for (int s = 0; s < 256; ++s) {
        int  t     = sample_row(g, s);
        bool valid = (t >= 0);
        int  tcl   = valid ? t : 0;
        int  addr  = g.col ? (tcl * WSZ + s) : (s * WSZ + tcl);
        float4 val = T4[addr * 4 + quad];
        if (valid) {            // plain adds, s-order == reference scan order
            acc.x += val.x;
            acc.y += val.y;
            acc.z += val.z;
            acc.w += val.w;
        }
    }

    int base = quad * 4;
    out[(base + 0) * NPIX + pix] = acc.x;
    out[(base + 1) * NPIX + pix] = acc.y;
    out[(base + 2) * NPIX + pix] = acc.z;
    out[(base + 3) * NPIX + pix] = acc.w;
}

// Fallback without workspace: direct scalar gathers from (bc,h,w).
__global__ __launch_bounds__(256) void epi_gather_direct(const float* __restrict__ x,
                                                         const float* __restrict__ F,
                                                         float* __restrict__ out) {
    int tid  = blockIdx.x * 256 + threadIdx.x;
    int quad = tid & 3;
    int pix  = tid >> 2;

    LineGeom g = make_geom(F, pix);

    float4 acc = make_float4(0.f, 0.f, 0.f, 0.f);
    int base = quad * 4;

#pragma unroll 2
    for (int s = 0; s < 256; ++s) {
        int  t     = sample_row(g, s);
        bool valid = (t >= 0);
        int  tcl   = valid ? t : 0;
        int  addr  = g.col ? (tcl * WSZ + s) : (s * WSZ + tcl);
        if (valid) {
            acc.x += x[(base + 0) * NPIX + addr];
            acc.y += x[(base + 1) * NPIX + addr];
            acc.z += x[(base + 2) * NPIX + addr];
            acc.w += x[(base + 3) * NPIX + addr];
        }
    }

    out[(base + 0) * NPIX + pix] = acc.x;
    out[(base + 1) * NPIX + pix] = acc.y;
    out[(base + 2) * NPIX + pix] = acc.z;
    out[(base + 3) * NPIX + pix] = acc.w;
}

extern "C" void kernel_launch(void* const* d_in, const int* in_sizes, int n_in,
                              void* d_out, int out_size, void* d_ws, size_t ws_size,
                              hipStream_t stream) {
    const float* x   = (const float*)d_in[0];
    const float* F   = (const float*)d_in[1];
    float*       out = (float*)d_out;

    const size_t need = (size_t)NELEM * sizeof(float);
    if (ws_size >= need) {
        float* T = (float*)d_ws;
        transpose_kernel<<<NELEM / 256, 256, 0, stream>>>(x, T);
        epi_gather<<<(NPIX * 4) / 256, 256, 0, stream>>>((const float4*)T, F, out);
    } else {
        epi_gather_direct<<<(NPIX * 4) / 256, 256, 0, stream>>>(x, F, out);
    }
}

// Round 7
// 98.239 us; speedup vs baseline: 1.5498x; 1.5498x over previous
//
#include <hip/hip_runtime.h>

// x: (2,8,256,256) fp32, F: 3x3 fp32.
#define HS 256
#define WSZ 256
#define NPIX (HS * WSZ)        // 65536 pixels
#define NCH 16                 // B*C
#define NELEM (NPIX * NCH)

// ---------------------------------------------------------------------------
// Transpose (bc, h, w) -> (h, w, bc), LDS-tiled: coalesced reads AND writes.
// Block = 256 threads handles 256 pixels (16 ch x 256 pix tile, 16.4 KB LDS).
// ---------------------------------------------------------------------------
__global__ __launch_bounds__(256) void transpose_kernel(const float* __restrict__ x,
                                                        float* __restrict__ T) {
    __shared__ float lds[16][257];   // +1 pad
    int tid  = threadIdx.x;
    int base = blockIdx.x * 256;
#pragma unroll
    for (int ch = 0; ch < 16; ++ch)
        lds[ch][tid] = x[ch * NPIX + base + tid];   // coalesced 1KB per instr
    __syncthreads();
    float4* T4 = (float4*)T;
#pragma unroll
    for (int it = 0; it < 4; ++it) {
        int idx = it * 256 + tid;    // 0..1023 float4s of this tile
        int p   = idx >> 2;          // local pixel
        int q   = idx & 3;           // channel quad
        float4 o;
        o.x = lds[q * 4 + 0][p];
        o.y = lds[q * 4 + 1][p];
        o.z = lds[q * 4 + 2][p];
        o.w = lds[q * 4 + 3][p];
        T4[base * 4 + idx] = o;      // contiguous 16B/lane -> coalesced
    }
}

// ---------------------------------------------------------------------------
// Geometry: FMA-contracted einsum (verified bit-exact in R6):
//   l_i = fma(F[1,i], v, F[0,i]*u) + F[2,i]
// ---------------------------------------------------------------------------
struct LineGeom {
    float p, q, c;
    bool  col;
};

__device__ __forceinline__ LineGeom make_geom(const float* __restrict__ F, int pix) {
#pragma clang fp contract(off)
    int w = pix & (WSZ - 1);
    int h = pix >> 8;
    float u = (float)w, v = (float)h;
    float a = __builtin_fmaf(F[3], v, F[0] * u) + F[6];
    float b = __builtin_fmaf(F[4], v, F[1] * u) + F[7];
    float c = __builtin_fmaf(F[5], v, F[2] * u) + F[8];
    const float eps = 1e-8f;
    float bs = (fabsf(b) < eps) ? eps : b;
    float as = (fabsf(a) < eps) ? eps : a;
    LineGeom g;
    g.col = (fabsf(b) >= fabsf(a));
    g.p   = g.col ? a : b;
    g.q   = g.col ? bs : as;
    g.c   = c;
    return g;
}

// Chain (verified bit-exact): t = fma(p,s,c); y = (-t)/q IEEE f32; rint; i32.
__device__ __forceinline__ int sample_row(const LineGeom& g, int s) {
#pragma clang fp contract(off)
    float sf = (float)s;
    float t  = __builtin_fmaf(g.p, sf, g.c);
    float y  = (-t) / g.q;
    float yr = __builtin_rintf(y);
    int   yi = (int)yr;
    return (yi >= 0 && yi < HS) ? yi : -1;   // -1 == invalid
}

// ---------------------------------------------------------------------------
// Gather: 8 threads per pixel = (quad 0..3) x (s-half 0..1). Each thread
// computes only s % 4 == quad chains of its half (4x dedup vs R6) and shares
// the index with its quad-group via __shfl; all 4 quads then load the 4 16B
// chunks of the SAME 64B line. Halves merged by shfl_xor(4) at the end.
// ---------------------------------------------------------------------------
__global__ __launch_bounds__(256) void epi_gather(const float4* __restrict__ T4,
                                                  const float* __restrict__ F,
                                                  float* __restrict__ out) {
    int tid  = blockIdx.x * 256 + threadIdx.x;
    int quad = tid & 3;
    int half = (tid >> 2) & 1;
    int pix  = tid >> 3;
    int lane = threadIdx.x & 63;

    LineGeom g = make_geom(F, pix);

    float4 acc = make_float4(0.f, 0.f, 0.f, 0.f);

    int sbase = half << 7;            // 0 or 128
    for (int k = 0; k < 32; ++k, sbase += 4) {
        int tmine = sample_row(g, sbase + quad);   // my 1/4 of the chains
#pragma unroll
        for (int j = 0; j < 4; ++j) {
            int   tj = __shfl(tmine, (lane & ~3) | j, 64);
            float m  = (tj >= 0) ? 1.0f : 0.0f;
            int   tc = max(tj, 0);
            int   s  = sbase + j;
            int   idx  = g.col ? ((tc << 8) | s) : ((s << 8) | tc);
            float4 val = T4[(idx << 2) | quad];    // 4 lanes share one 64B line
            acc.x = __builtin_fmaf(val.x, m, acc.x);
            acc.y = __builtin_fmaf(val.y, m, acc.y);
            acc.z = __builtin_fmaf(val.z, m, acc.z);
            acc.w = __builtin_fmaf(val.w, m, acc.w);
        }
    }

    // merge the two s-halves (lane ^ 4 is same pixel/quad, other half)
    acc.x += __shfl_xor(acc.x, 4, 64);
    acc.y += __shfl_xor(acc.y, 4, 64);
    acc.z += __shfl_xor(acc.z, 4, 64);
    acc.w += __shfl_xor(acc.w, 4, 64);

    if (half == 0) {
        int ch = quad * 4;
        out[(ch + 0) * NPIX + pix] = acc.x;
        out[(ch + 1) * NPIX + pix] = acc.y;
        out[(ch + 2) * NPIX + pix] = acc.z;
        out[(ch + 3) * NPIX + pix] = acc.w;
    }
}

// Fallback without workspace: direct scalar gathers from (bc,h,w).
__global__ __launch_bounds__(256) void epi_gather_direct(const float* __restrict__ x,
                                                         const float* __restrict__ F,
                                                         float* __restrict__ out) {
    int tid  = blockIdx.x * 256 + threadIdx.x;
    int quad = tid & 3;
    int pix  = tid >> 2;

    LineGeom g = make_geom(F, pix);

    float4 acc = make_float4(0.f, 0.f, 0.f, 0.f);
    int base = quad * 4;

#pragma unroll 2
    for (int s = 0; s < 256; ++s) {
        int  t     = sample_row(g, s);
        bool valid = (t >= 0);
        int  tcl   = valid ? t : 0;
        int  addr  = g.col ? (tcl * WSZ + s) : (s * WSZ + tcl);
        if (valid) {
            acc.x += x[(base + 0) * NPIX + addr];
            acc.y += x[(base + 1) * NPIX + addr];
            acc.z += x[(base + 2) * NPIX + addr];
            acc.w += x[(base + 3) * NPIX + addr];
        }
    }

    out[(base + 0) * NPIX + pix] = acc.x;
    out[(base + 1) * NPIX + pix] = acc.y;
    out[(base + 2) * NPIX + pix] = acc.z;
    out[(base + 3) * NPIX + pix] = acc.w;
}

extern "C" void kernel_launch(void* const* d_in, const int* in_sizes, int n_in,
                              void* d_out, int out_size, void* d_ws, size_t ws_size,
                              hipStream_t stream) {
    const float* x   = (const float*)d_in[0];
    const float* F   = (const float*)d_in[1];
    float*       out = (float*)d_out;

    const size_t need = (size_t)NELEM * sizeof(float);
    if (ws_size >= need) {
        float* T = (float*)d_ws;
        transpose_kernel<<<NPIX / 256, 256, 0, stream>>>(x, T);
        epi_gather<<<(NPIX * 8) / 256, 256, 0, stream>>>((const float4*)T, F, out);
    } else {
        epi_gather_direct<<<(NPIX * 4) / 256, 256, 0, stream>>>(x, F, out);
    }
}

// Round 8
// 98.081 us; speedup vs baseline: 1.5523x; 1.0016x over previous
//
#include <hip/hip_runtime.h>

// x: (2,8,256,256) fp32, F: 3x3 fp32.
#define HS 256
#define WSZ 256
#define NPIX (HS * WSZ)        // 65536 pixels
#define NCH 16                 // B*C
#define NELEM (NPIX * NCH)

// ---------------------------------------------------------------------------
// Transpose (bc, h, w) -> (h, w, bc), LDS-tiled, coalesced both sides.
// Also writes a 64 B zero line at T[NELEM..NELEM+15] (invalid-sample target) —
// must happen every launch because d_ws is re-poisoned to 0xAA.
// ---------------------------------------------------------------------------
__global__ __launch_bounds__(256) void transpose_kernel(const float* __restrict__ x,
                                                        float* __restrict__ T) {
    __shared__ float lds[16][257];   // +1 pad
    int tid  = threadIdx.x;
    int base = blockIdx.x * 256;
#pragma unroll
    for (int ch = 0; ch < 16; ++ch)
        lds[ch][tid] = x[ch * NPIX + base + tid];   // coalesced 1KB per instr
    if (blockIdx.x == 0 && tid < 16) T[NELEM + tid] = 0.0f;  // zero line
    __syncthreads();
    float4* T4 = (float4*)T;
#pragma unroll
    for (int it = 0; it < 4; ++it) {
        int idx = it * 256 + tid;    // 0..1023 float4s of this tile
        int p   = idx >> 2;          // local pixel
        int q   = idx & 3;           // channel quad
        float4 o;
        o.x = lds[q * 4 + 0][p];
        o.y = lds[q * 4 + 1][p];
        o.z = lds[q * 4 + 2][p];
        o.w = lds[q * 4 + 3][p];
        T4[base * 4 + idx] = o;      // contiguous 16B/lane -> coalesced
    }
}

// ---------------------------------------------------------------------------
// Geometry (bit-exact, verified R6): FMA-contracted einsum, f32.
// ---------------------------------------------------------------------------
struct LineGeom {
    float p, q, c;
    bool  col;
};

__device__ __forceinline__ LineGeom make_geom(const float* __restrict__ F, int pix) {
#pragma clang fp contract(off)
    int w = pix & (WSZ - 1);
    int h = pix >> 8;
    float u = (float)w, v = (float)h;
    float a = __builtin_fmaf(F[3], v, F[0] * u) + F[6];
    float b = __builtin_fmaf(F[4], v, F[1] * u) + F[7];
    float c = __builtin_fmaf(F[5], v, F[2] * u) + F[8];
    const float eps = 1e-8f;
    float bs = (fabsf(b) < eps) ? eps : b;
    float as = (fabsf(a) < eps) ? eps : a;
    LineGeom g;
    g.col = (fabsf(b) >= fabsf(a));
    g.p   = g.col ? a : b;
    g.q   = g.col ? bs : as;
    g.c   = c;
    return g;
}

// Chain (bit-exact, verified R6): t = fma(p,s,c); y = (-t)/q IEEE f32; rint; i32.
__device__ __forceinline__ int sample_row(const LineGeom& g, int s) {
#pragma clang fp contract(off)
    float sf = (float)s;
    float t  = __builtin_fmaf(g.p, sf, g.c);
    float y  = (-t) / g.q;
    float yr = __builtin_rintf(y);
    int   yi = (int)yr;
    return (yi >= 0 && yi < HS) ? yi : -1;   // -1 == invalid
}

// ---------------------------------------------------------------------------
// Gather: 8 threads per pixel = (quad 0..3) x (s-half 0..1); thread computes
// s%4==quad chains of its half; quad-group shares the row index via DPP
// quad_perm broadcast (pure VALU, no DS pipe); 4 quads load the 4 16B chunks
// of one 64B line; invalid samples redirect to the zero line.
// ---------------------------------------------------------------------------
#define QUAD_BCAST(dst, src, ctrl)                                              \
    dst = __builtin_amdgcn_mov_dpp(src, ctrl, 0xf, 0xf, false)

__global__ __launch_bounds__(256) void epi_gather(const float4* __restrict__ T4,
                                                  const float* __restrict__ F,
                                                  float* __restrict__ out) {
    int tid  = blockIdx.x * 256 + threadIdx.x;
    int quad = tid & 3;
    int half = (tid >> 2) & 1;
    int pix  = tid >> 3;

    LineGeom g = make_geom(F, pix);

    int tMul = g.col ? WSZ : 1;      // addr = t*tMul + s*sMul (pixel-uniform)
    int sMul = g.col ? 1 : WSZ;
    const int zeroF4 = NPIX * 4 + quad;  // float4 idx inside the zero line

    float4 acc = make_float4(0.f, 0.f, 0.f, 0.f);

    int schain = (half << 7) + quad;     // s of my chain
    int sOff   = (half << 7) * sMul;     // s*sMul for j=0

#pragma unroll 4
    for (int k = 0; k < 32; ++k) {
        int tmine = sample_row(g, schain);
        schain += 4;
        int tj, fidx;
        float4 val;
#define J_STEP(CTRL)                                                            \
        QUAD_BCAST(tj, tmine, CTRL);                                            \
        fidx = (((tj & 255) * tMul + sOff) << 2) + quad;                        \
        fidx = (tj >= 0) ? fidx : zeroF4;                                       \
        val  = T4[fidx];                                                        \
        acc.x += val.x; acc.y += val.y; acc.z += val.z; acc.w += val.w;         \
        sOff += sMul;
        J_STEP(0x00)   // quad_perm [0,0,0,0]
        J_STEP(0x55)   // quad_perm [1,1,1,1]
        J_STEP(0xAA)   // quad_perm [2,2,2,2]
        J_STEP(0xFF)   // quad_perm [3,3,3,3]
#undef J_STEP
    }

    // merge the two s-halves (lane ^ 4 = same pixel/quad, other half)
    acc.x += __shfl_xor(acc.x, 4, 64);
    acc.y += __shfl_xor(acc.y, 4, 64);
    acc.z += __shfl_xor(acc.z, 4, 64);
    acc.w += __shfl_xor(acc.w, 4, 64);

    if (half == 0) {
        int ch = quad * 4;
        out[(ch + 0) * NPIX + pix] = acc.x;
        out[(ch + 1) * NPIX + pix] = acc.y;
        out[(ch + 2) * NPIX + pix] = acc.z;
        out[(ch + 3) * NPIX + pix] = acc.w;
    }
}

// Fallback without workspace: direct scalar gathers from (bc,h,w).
__global__ __launch_bounds__(256) void epi_gather_direct(const float* __restrict__ x,
                                                         const float* __restrict__ F,
                                                         float* __restrict__ out) {
    int tid  = blockIdx.x * 256 + threadIdx.x;
    int quad = tid & 3;
    int pix  = tid >> 2;

    LineGeom g = make_geom(F, pix);

    float4 acc = make_float4(0.f, 0.f, 0.f, 0.f);
    int base = quad * 4;

#pragma unroll 2
    for (int s = 0; s < 256; ++s) {
        int  t     = sample_row(g, s);
        bool valid = (t >= 0);
        int  tcl   = valid ? t : 0;
        int  addr  = g.col ? (tcl * WSZ + s) : (s * WSZ + tcl);
        if (valid) {
            acc.x += x[(base + 0) * NPIX + addr];
            acc.y += x[(base + 1) * NPIX + addr];
            acc.z += x[(base + 2) * NPIX + addr];
            acc.w += x[(base + 3) * NPIX + addr];
        }
    }

    out[(base + 0) * NPIX + pix] = acc.x;
    out[(base + 1) * NPIX + pix] = acc.y;
    out[(base + 2) * NPIX + pix] = acc.z;
    out[(base + 3) * NPIX + pix] = acc.w;
}

extern "C" void kernel_launch(void* const* d_in, const int* in_sizes, int n_in,
                              void* d_out, int out_size, void* d_ws, size_t ws_size,
                              hipStream_t stream) {
    const float* x   = (const float*)d_in[0];
    const float* F   = (const float*)d_in[1];
    float*       out = (float*)d_out;

    const size_t need = (size_t)(NELEM + 16) * sizeof(float);
    if (ws_size >= need) {
        float* T = (float*)d_ws;
        transpose_kernel<<<NPIX / 256, 256, 0, stream>>>(x, T);
        epi_gather<<<(NPIX * 8) / 256, 256, 0, stream>>>((const float4*)T, F, out);
    } else {
        epi_gather_direct<<<(NPIX * 4) / 256, 256, 0, stream>>>(x, F, out);
    }
}

// Round 9
// 94.974 us; speedup vs baseline: 1.6031x; 1.0327x over previous
//
#include <hip/hip_runtime.h>

// x: (2,8,256,256) fp32, F: 3x3 fp32.
#define HS 256
#define WSZ 256
#define NPIX (HS * WSZ)        // 65536 pixels
#define NCH 16                 // B*C
#define NELEM (NPIX * NCH)

// ---------------------------------------------------------------------------
// Transpose (bc, h, w) -> (h, w, bc), LDS-tiled, coalesced both sides.
// Also writes a 64 B zero line at T[NELEM..NELEM+15] (invalid-sample target) —
// must happen every launch because d_ws is re-poisoned to 0xAA.
// ---------------------------------------------------------------------------
__global__ __launch_bounds__(256) void transpose_kernel(const float* __restrict__ x,
                                                        float* __restrict__ T) {
    __shared__ float lds[16][257];   // +1 pad
    int tid  = threadIdx.x;
    int base = blockIdx.x * 256;
#pragma unroll
    for (int ch = 0; ch < 16; ++ch)
        lds[ch][tid] = x[ch * NPIX + base + tid];   // coalesced 1KB per instr
    if (blockIdx.x == 0 && tid < 16) T[NELEM + tid] = 0.0f;  // zero line
    __syncthreads();
    float4* T4 = (float4*)T;
#pragma unroll
    for (int it = 0; it < 4; ++it) {
        int idx = it * 256 + tid;    // 0..1023 float4s of this tile
        int p   = idx >> 2;          // local pixel
        int q   = idx & 3;           // channel quad
        float4 o;
        o.x = lds[q * 4 + 0][p];
        o.y = lds[q * 4 + 1][p];
        o.z = lds[q * 4 + 2][p];
        o.w = lds[q * 4 + 3][p];
        T4[base * 4 + idx] = o;      // contiguous 16B/lane -> coalesced
    }
}

// ---------------------------------------------------------------------------
// Geometry (bit-exact, verified R6): FMA-contracted einsum, f32.
// ---------------------------------------------------------------------------
struct LineGeom {
    float p, q, c;
    bool  col;
};

__device__ __forceinline__ LineGeom make_geom(const float* __restrict__ F, int pix) {
#pragma clang fp contract(off)
    int w = pix & (WSZ - 1);
    int h = pix >> 8;
    float u = (float)w, v = (float)h;
    float a = __builtin_fmaf(F[3], v, F[0] * u) + F[6];
    float b = __builtin_fmaf(F[4], v, F[1] * u) + F[7];
    float c = __builtin_fmaf(F[5], v, F[2] * u) + F[8];
    const float eps = 1e-8f;
    float bs = (fabsf(b) < eps) ? eps : b;
    float as = (fabsf(a) < eps) ? eps : a;
    LineGeom g;
    g.col = (fabsf(b) >= fabsf(a));
    g.p   = g.col ? a : b;
    g.q   = g.col ? bs : as;
    g.c   = c;
    return g;
}

// Chain (bit-exact, verified R6): t = fma(p,s,c); y = (-t)/q IEEE f32; rint; i32.
__device__ __forceinline__ int sample_row(const LineGeom& g, int s) {
#pragma clang fp contract(off)
    float sf = (float)s;
    float t  = __builtin_fmaf(g.p, sf, g.c);
    float y  = (-t) / g.q;
    float yr = __builtin_rintf(y);
    int   yi = (int)yr;
    return (yi >= 0 && yi < HS) ? yi : -1;   // -1 == invalid
}

// ---------------------------------------------------------------------------
// Gather: 16 threads per pixel = (quad 0..3) x (s-quarter 0..3). Each thread
// computes s%4==quad chains of its quarter (full dedup), shares indices with
// its quad-group via DPP quad_perm broadcast, and batches 8 float4 loads into
// an explicit array before accumulating (forces deep MLP). Invalid samples
// redirect to the zero line. Quarters merged via shfl_xor(8) + shfl_xor(4).
// ---------------------------------------------------------------------------
#define QUAD_BCAST(dst, src, ctrl)                                              \
    dst = __builtin_amdgcn_mov_dpp(src, ctrl, 0xf, 0xf, false)

__global__ __launch_bounds__(256) void epi_gather(const float4* __restrict__ T4,
                                                  const float* __restrict__ F,
                                                  float* __restrict__ out) {
    int tid  = blockIdx.x * 256 + threadIdx.x;
    int quad = tid & 3;
    int sq   = (tid >> 2) & 3;           // s-quarter
    int pix  = tid >> 4;

    LineGeom g = make_geom(F, pix);

    int tMul = g.col ? WSZ : 1;          // addr = t*tMul + s*sMul (pixel-uniform)
    int sMul = g.col ? 1 : WSZ;
    const int zeroF4 = NPIX * 4 + quad;  // float4 idx inside the zero line

    float4 acc = make_float4(0.f, 0.f, 0.f, 0.f);

    int schain = (sq << 6) + quad;       // s of my chains: sq*64 + quad + 4k
    int sOff   = (sq << 6) * sMul;       // s*sMul for j=0 of this batch

#pragma unroll 2
    for (int m = 0; m < 8; ++m) {
        int t0 = sample_row(g, schain); schain += 4;
        int t1 = sample_row(g, schain); schain += 4;
        int f[8];
        int tj;
#define IDX(dst, src, CTRL, J)                                                  \
        QUAD_BCAST(tj, src, CTRL);                                              \
        dst = (((tj & 255) * tMul + sOff + (J) * sMul) << 2) + quad;            \
        dst = (tj >= 0) ? dst : zeroF4;
        IDX(f[0], t0, 0x00, 0) IDX(f[1], t0, 0x55, 1)
        IDX(f[2], t0, 0xAA, 2) IDX(f[3], t0, 0xFF, 3)
        IDX(f[4], t1, 0x00, 4) IDX(f[5], t1, 0x55, 5)
        IDX(f[6], t1, 0xAA, 6) IDX(f[7], t1, 0xFF, 7)
#undef IDX
        // batch-issue 8 independent 16B loads (L1-line-sharing across quads)
        float4 v0 = T4[f[0]], v1 = T4[f[1]], v2 = T4[f[2]], v3 = T4[f[3]];
        float4 v4 = T4[f[4]], v5 = T4[f[5]], v6 = T4[f[6]], v7 = T4[f[7]];
        // accumulate in ascending-s order
        acc.x += v0.x; acc.y += v0.y; acc.z += v0.z; acc.w += v0.w;
        acc.x += v1.x; acc.y += v1.y; acc.z += v1.z; acc.w += v1.w;
        acc.x += v2.x; acc.y += v2.y; acc.z += v2.z; acc.w += v2.w;
        acc.x += v3.x; acc.y += v3.y; acc.z += v3.z; acc.w += v3.w;
        acc.x += v4.x; acc.y += v4.y; acc.z += v4.z; acc.w += v4.w;
        acc.x += v5.x; acc.y += v5.y; acc.z += v5.z; acc.w += v5.w;
        acc.x += v6.x; acc.y += v6.y; acc.z += v6.z; acc.w += v6.w;
        acc.x += v7.x; acc.y += v7.y; acc.z += v7.z; acc.w += v7.w;
        sOff += 8 * sMul;
    }

    // merge the four s-quarters: lane^8 flips sq bit1, lane^4 flips sq bit0
    acc.x += __shfl_xor(acc.x, 8, 64);
    acc.y += __shfl_xor(acc.y, 8, 64);
    acc.z += __shfl_xor(acc.z, 8, 64);
    acc.w += __shfl_xor(acc.w, 8, 64);
    acc.x += __shfl_xor(acc.x, 4, 64);
    acc.y += __shfl_xor(acc.y, 4, 64);
    acc.z += __shfl_xor(acc.z, 4, 64);
    acc.w += __shfl_xor(acc.w, 4, 64);

    if (sq == 0) {
        int ch = quad * 4;
        out[(ch + 0) * NPIX + pix] = acc.x;
        out[(ch + 1) * NPIX + pix] = acc.y;
        out[(ch + 2) * NPIX + pix] = acc.z;
        out[(ch + 3) * NPIX + pix] = acc.w;
    }
}

// Fallback without workspace: direct scalar gathers from (bc,h,w).
__global__ __launch_bounds__(256) void epi_gather_direct(const float* __restrict__ x,
                                                         const float* __restrict__ F,
                                                         float* __restrict__ out) {
    int tid  = blockIdx.x * 256 + threadIdx.x;
    int quad = tid & 3;
    int pix  = tid >> 2;

    LineGeom g = make_geom(F, pix);

    float4 acc = make_float4(0.f, 0.f, 0.f, 0.f);
    int base = quad * 4;

#pragma unroll 2
    for (int s = 0; s < 256; ++s) {
        int  t     = sample_row(g, s);
        bool valid = (t >= 0);
        int  tcl   = valid ? t : 0;
        int  addr  = g.col ? (tcl * WSZ + s) : (s * WSZ + tcl);
        if (valid) {
            acc.x += x[(base + 0) * NPIX + addr];
            acc.y += x[(base + 1) * NPIX + addr];
            acc.z += x[(base + 2) * NPIX + addr];
            acc.w += x[(base + 3) * NPIX + addr];
        }
    }

    out[(base + 0) * NPIX + pix] = acc.x;
    out[(base + 1) * NPIX + pix] = acc.y;
    out[(base + 2) * NPIX + pix] = acc.z;
    out[(base + 3) * NPIX + pix] = acc.w;
}

extern "C" void kernel_launch(void* const* d_in, const int* in_sizes, int n_in,
                              void* d_out, int out_size, void* d_ws, size_t ws_size,
                              hipStream_t stream) {
    const float* x   = (const float*)d_in[0];
    const float* F   = (const float*)d_in[1];
    float*       out = (float*)d_out;

    const size_t need = (size_t)(NELEM + 16) * sizeof(float);
    if (ws_size >= need) {
        float* T = (float*)d_ws;
        transpose_kernel<<<NPIX / 256, 256, 0, stream>>>(x, T);
        epi_gather<<<(NPIX * 16) / 256, 256, 0, stream>>>((const float4*)T, F, out);
    } else {
        epi_gather_direct<<<(NPIX * 4) / 256, 256, 0, stream>>>(x, F, out);
    }
}